// Round 3
// baseline (523.674 us; speedup 1.0000x reference)
//
#include <hip/hip_runtime.h>

typedef short bf16x8 __attribute__((ext_vector_type(8)));
typedef float f32x4 __attribute__((ext_vector_type(4)));
typedef unsigned u32;
typedef unsigned short u16;
typedef unsigned u32x4v __attribute__((ext_vector_type(4)));

union UV { u32x4v u; bf16x8 v; };

__device__ __forceinline__ u16 f2bf(float f){          // RNE fp32->bf16
  u32 u = __float_as_uint(f);
  u += 0x7FFFu + ((u>>16)&1u);
  return (u16)(u>>16);
}
__device__ __forceinline__ u32 pack2(float lo, float hi){
  return (u32)f2bf(lo) | ((u32)f2bf(hi)<<16);
}
__device__ __forceinline__ bf16x8 cvt8(float4 lo, float4 hi){
  UV t; t.u = (u32x4v){ pack2(lo.x,lo.y), pack2(lo.z,lo.w), pack2(hi.x,hi.y), pack2(hi.z,hi.w) };
  return t.v;
}

// ---------------- K0a: q_scaled[n][d] = SCALE*(emb[n,:]·q_w[d,:] + q_b[d]) -> bf16 ----------------
__global__ void k_qs(const float* __restrict__ emb, const float* __restrict__ q_w,
                     const float* __restrict__ q_b, u16* __restrict__ q_s){
  const int n = blockIdx.x;      // 64
  const int d = threadIdx.x;     // 256
  const float4* er = (const float4*)(emb + n*256);
  const float4* wr = (const float4*)(q_w + d*256);
  float acc = 0.f;
  for(int c=0;c<64;++c){
    float4 e = er[c], w = wr[c];
    acc += e.x*w.x + e.y*w.y + e.z*w.z + e.w*w.w;
  }
  acc += q_b[d];
  q_s[n*256 + d] = f2bf(acc * 0.17677669529663687f);   // 32^-0.5
}

// ---------------- K0b: bias[h][n][m] = rpb[rel_idx(n,m)][h] (fp32) ----------------
__global__ void k_bias(const float* __restrict__ rpb, float* __restrict__ bias){
  const int o = blockIdx.x*256 + threadIdx.x;          // 128 blocks -> 32768
  const int h = o>>12, n = (o>>6)&63, m = o&63;
  const int idx = ((n>>3)-(m>>3)+7)*15 + ((n&7)-(m&7)+7);
  bias[o] = rpb[idx*8 + h];
}

// ---------------- K0c: convert kv_w (131072 f32) and proj_w (65536 f32) to bf16 ----------------
__global__ void k_wcvt(const float* __restrict__ kv_w, const float* __restrict__ proj_w,
                       u32* __restrict__ kvb, u32* __restrict__ pjb){
  const int i = blockIdx.x*256 + threadIdx.x;          // 384 blocks -> 98304
  if(i < 65536) kvb[i] = pack2(kv_w[2*i], kv_w[2*i+1]);
  else { int j = i - 65536; pjb[j] = pack2(proj_w[2*j], proj_w[2*j+1]); }
}

// ---------------- K1: per-window KV GEMM -> k_ws (row-major bf16), vT_ws (transposed bf16) ----------------
// win[bw,n,c] = x[ b*4194304 + h1*262144 + (n>>3)*32768 + w1*2048 + (n&7)*256 + c ]
__global__ __launch_bounds__(256,2) void k_kv(const float* __restrict__ x, const u16* __restrict__ kvw,
                                              const float* __restrict__ kv_b, u16* __restrict__ k_ws,
                                              u16* __restrict__ vT_ws){
  const int bw = blockIdx.x;
  const int b = bw>>8, h1 = (bw>>4)&15, w1 = bw&15;
  const int base = b*4194304 + h1*262144 + w1*2048;
  const int tid = threadIdx.x;
  const int w = tid>>6, l = tid&63, g = l>>4, li = l&15;

  f32x4 acc[4][8];
  #pragma unroll
  for(int ct=0;ct<8;++ct){
    float bv = kv_b[w*128 + ct*16 + li];
    #pragma unroll
    for(int rt=0;rt<4;++rt) acc[rt][ct] = (f32x4){bv,bv,bv,bv};
  }
  for(int ks=0;ks<8;++ks){
    bf16x8 a[4];
    #pragma unroll
    for(int rt=0;rt<4;++rt){
      int n = rt*16 + li;
      const float* ap = x + base + (n>>3)*32768 + (n&7)*256 + ks*32 + g*8;
      a[rt] = cvt8(*(const float4*)ap, *(const float4*)(ap+4));
    }
    #pragma unroll
    for(int ct=0;ct<8;++ct){
      bf16x8 bfr = *(const bf16x8*)(kvw + (w*128 + ct*16 + li)*256 + ks*32 + g*8);
      #pragma unroll
      for(int rt=0;rt<4;++rt)
        acc[rt][ct] = __builtin_amdgcn_mfma_f32_16x16x32_bf16(a[rt], bfr, acc[rt][ct], 0,0,0);
    }
  }
  #pragma unroll
  for(int ct=0;ct<8;++ct){
    int col = w*128 + ct*16 + li;
    if(col < 256){            // k half (waves 0,1) -> row-major k_ws[token][col]
      #pragma unroll
      for(int rt=0;rt<4;++rt)
        #pragma unroll
        for(int r=0;r<4;++r)
          k_ws[(bw*64 + rt*16 + 4*g + r)*256 + col] = f2bf(acc[rt][ct][r]);
    } else {                  // v half (waves 2,3) -> vT_ws[bw][h][e][m], 4 contiguous m per lane
      int c2 = col-256, h = c2>>5, e = c2&31;
      #pragma unroll
      for(int rt=0;rt<4;++rt){
        u32 lo = pack2(acc[rt][ct][0], acc[rt][ct][1]);
        u32 hi = pack2(acc[rt][ct][2], acc[rt][ct][3]);
        u32* p = (u32*)(vT_ws + ((bw*8 + h)*32 + e)*64 + rt*16 + 4*g);
        p[0] = lo; p[1] = hi;
      }
    }
  }
}

// ---------------- K2: per-window attention (wave w does heads w and w+4) ----------------
__global__ __launch_bounds__(256,2) void k_attn(const u16* __restrict__ q_s, const u16* __restrict__ k_ws,
                                                const u16* __restrict__ vT_ws, const float* __restrict__ bias,
                                                u16* __restrict__ ao){
  __shared__ u32 Ps[4][64*36];   // per-wave P buffer, row stride 36 u32 (=72 bf16, 16B aligned)
  const int bw = blockIdx.x;
  const int tid = threadIdx.x, w = tid>>6, l = tid&63, g = l>>4, li = l&15;
  u32* pb = Ps[w];

  #pragma unroll 1
  for(int hh=0; hh<2; ++hh){
    const int h = w + 4*hh;
    bf16x8 qf[4], kf[4];
    #pragma unroll
    for(int rt=0;rt<4;++rt) qf[rt] = *(const bf16x8*)(q_s + (rt*16+li)*256 + h*32 + g*8);
    #pragma unroll
    for(int ct=0;ct<4;++ct) kf[ct] = *(const bf16x8*)(k_ws + (bw*64 + ct*16+li)*256 + h*32 + g*8);

    // S = q_scaled · k^T, accumulator initialized with bias
    f32x4 S[4][4];
    #pragma unroll
    for(int rt=0;rt<4;++rt){
      #pragma unroll
      for(int ct=0;ct<4;++ct){
        const float* bp = bias + h*4096 + (rt*16 + 4*g)*64 + ct*16 + li;
        f32x4 c = { bp[0], bp[64], bp[128], bp[192] };
        S[rt][ct] = __builtin_amdgcn_mfma_f32_16x16x32_bf16(qf[rt], kf[ct], c, 0,0,0);
      }
    }
    // in-register softmax: row n = rt*16+4g+r lives in the 16-lane (li) group
    float rs[4][4];
    #pragma unroll
    for(int rt=0;rt<4;++rt){
      #pragma unroll
      for(int r=0;r<4;++r){
        float m_ = fmaxf(fmaxf(S[rt][0][r],S[rt][1][r]), fmaxf(S[rt][2][r],S[rt][3][r]));
        m_ = fmaxf(m_, __shfl_xor(m_,1));
        m_ = fmaxf(m_, __shfl_xor(m_,2));
        m_ = fmaxf(m_, __shfl_xor(m_,4));
        m_ = fmaxf(m_, __shfl_xor(m_,8));
        float e0 = __expf(S[rt][0][r]-m_), e1 = __expf(S[rt][1][r]-m_);
        float e2 = __expf(S[rt][2][r]-m_), e3 = __expf(S[rt][3][r]-m_);
        S[rt][0][r]=e0; S[rt][1][r]=e1; S[rt][2][r]=e2; S[rt][3][r]=e3;
        float s_ = e0+e1+e2+e3;
        s_ += __shfl_xor(s_,1); s_ += __shfl_xor(s_,2); s_ += __shfl_xor(s_,4); s_ += __shfl_xor(s_,8);
        rs[rt][r] = 1.0f/s_;
      }
    }
    // C-layout -> A-layout transpose of P via LDS; lane-paired u32 writes
    const int odd = l & 1;
    #pragma unroll
    for(int rt=0;rt<4;++rt){
      #pragma unroll
      for(int ct=0;ct<4;++ct){
        float v0=S[rt][ct][0], v1=S[rt][ct][1], v2=S[rt][ct][2], v3=S[rt][ct][3];
        float o0=__shfl_xor(v0,1), o1=__shfl_xor(v1,1), o2=__shfl_xor(v2,1), o3=__shfl_xor(v3,1);
        u32 d0 = odd ? pack2(o2,v2) : pack2(v0,o0);
        u32 d1 = odd ? pack2(o3,v3) : pack2(v1,o1);
        int r0 = odd ? 2 : 0;
        int cp = ct*8 + (li>>1);
        pb[(rt*16 + 4*g + r0    )*36 + cp] = d0;
        pb[(rt*16 + 4*g + r0 + 1)*36 + cp] = d1;
      }
    }
    // O = P · v  (B-frags contiguous from vT_ws)
    f32x4 O[4][2];
    #pragma unroll
    for(int rt=0;rt<4;++rt){ O[rt][0]=(f32x4){0,0,0,0}; O[rt][1]=(f32x4){0,0,0,0}; }
    #pragma unroll
    for(int ks=0;ks<2;++ks){
      bf16x8 pf[4];
      #pragma unroll
      for(int rt=0;rt<4;++rt){
        UV t; t.u = *(const u32x4v*)(pb + (rt*16+li)*36 + ks*16 + g*4);
        pf[rt] = t.v;
      }
      #pragma unroll
      for(int c2=0;c2<2;++c2){
        bf16x8 vf = *(const bf16x8*)(vT_ws + ((bw*8 + h)*32 + c2*16 + li)*64 + ks*32 + g*8);
        #pragma unroll
        for(int rt=0;rt<4;++rt)
          O[rt][c2] = __builtin_amdgcn_mfma_f32_16x16x32_bf16(pf[rt], vf, O[rt][c2], 0,0,0);
      }
    }
    // epilogue: divide by softmax denom (row mapping matches S), store
    #pragma unroll
    for(int rt=0;rt<4;++rt)
      #pragma unroll
      for(int c2=0;c2<2;++c2)
        #pragma unroll
        for(int r=0;r<4;++r)
          ao[(bw*64 + rt*16 + 4*g + r)*256 + h*32 + c2*16 + li] = f2bf(O[rt][c2][r]*rs[rt][r]);
  }
}

// ---------------- K3: per-window proj GEMM -> d_out (fp32) ----------------
__global__ __launch_bounds__(256,2) void k_proj(const u16* __restrict__ ao, const u16* __restrict__ pjw,
                                                const float* __restrict__ proj_b, float* __restrict__ out){
  const int bw = blockIdx.x;
  const int tid = threadIdx.x, w = tid>>6, l = tid&63, g = l>>4, li = l&15;
  f32x4 acc[4][4];
  #pragma unroll
  for(int ct=0;ct<4;++ct){
    float bv = proj_b[w*64 + ct*16 + li];
    #pragma unroll
    for(int rt=0;rt<4;++rt) acc[rt][ct] = (f32x4){bv,bv,bv,bv};
  }
  for(int ks=0;ks<8;++ks){
    bf16x8 a[4];
    #pragma unroll
    for(int rt=0;rt<4;++rt) a[rt] = *(const bf16x8*)(ao + (bw*64 + rt*16 + li)*256 + ks*32 + g*8);
    #pragma unroll
    for(int ct=0;ct<4;++ct){
      bf16x8 bfr = *(const bf16x8*)(pjw + (w*64 + ct*16 + li)*256 + ks*32 + g*8);
      #pragma unroll
      for(int rt=0;rt<4;++rt)
        acc[rt][ct] = __builtin_amdgcn_mfma_f32_16x16x32_bf16(a[rt], bfr, acc[rt][ct], 0,0,0);
    }
  }
  #pragma unroll
  for(int rt=0;rt<4;++rt)
    #pragma unroll
    for(int ct=0;ct<4;++ct)
      #pragma unroll
      for(int r=0;r<4;++r)
        out[(bw*64 + rt*16 + 4*g + r)*256 + w*64 + ct*16 + li] = acc[rt][ct][r];
}

extern "C" void kernel_launch(void* const* d_in, const int* in_sizes, int n_in,
                              void* d_out, int out_size, void* d_ws, size_t ws_size,
                              hipStream_t stream){
  (void)in_sizes; (void)n_in; (void)out_size;
  const float* x      = (const float*)d_in[0];
  const float* emb    = (const float*)d_in[1];
  const float* rpb    = (const float*)d_in[2];
  const float* q_w    = (const float*)d_in[3];
  const float* q_b    = (const float*)d_in[4];
  const float* kv_w   = (const float*)d_in[5];
  const float* kv_b   = (const float*)d_in[6];
  const float* proj_w = (const float*)d_in[7];
  const float* proj_b = (const float*)d_in[8];
  float* out = (float*)d_out;

  // ws layout (bytes): q_s 32K | bias 128K | kvw_bf 256K | pjw_bf 128K | k_ws 64M | vT 64M | ao 64M
  char* ws = (char*)d_ws;
  const size_t KV_BYTES = 67108864;
  if(ws_size < (size_t)557056 + 3*KV_BYTES) return;   // diagnostic: out stays zero if ws too small
  u16* q_s   = (u16*)(ws);
  float* bias= (float*)(ws + 32768);
  u32* kvb   = (u32*)(ws + 163840);
  u32* pjb   = (u32*)(ws + 425984);
  u16* k_ws  = (u16*)(ws + 557056);
  u16* vT    = (u16*)(ws + 557056 + KV_BYTES);
  u16* ao    = (u16*)(ws + 557056 + 2*KV_BYTES);

  k_qs  <<<  64, 256, 0, stream>>>(emb, q_w, q_b, q_s);
  k_bias<<< 128, 256, 0, stream>>>(rpb, bias);
  k_wcvt<<< 384, 256, 0, stream>>>(kv_w, proj_w, kvb, pjb);
  k_kv  <<<2048, 256, 0, stream>>>(x, (const u16*)kvb, kv_b, k_ws, vT);
  k_attn<<<2048, 256, 0, stream>>>(q_s, k_ws, vT, bias, ao);
  k_proj<<<2048, 256, 0, stream>>>(ao, (const u16*)pjb, proj_b, out);
}